// Round 6
// baseline (1026.634 us; speedup 1.0000x reference)
//
#include <hip/hip_runtime.h>
#include <math.h>

// ---------------- problem constants ----------------
#define BATCH   16
#define DMODEL  512
#define EKEY    128
#define HWSZ    484
#define LENC    1452
#define LKPAD   1536                       // padded key length (12 x 128)
#define IMG_ELEMS (HWSZ*BATCH*DMODEL)      // 3,964,928 floats per image [484][16][512]
#define ENC_OUT   11894784ull
#define SQRT_TEMP 5.4772255750516611f      // sqrt(30) folded into both projections
#define INORM_SCALE 0.011048543456039806f  // sqrt(1/(512*16))
#define NEGBIG   -3.0e38f

typedef _Float16 f16;
typedef _Float16 f16x8 __attribute__((ext_vector_type(8)));
typedef _Float16 f16x4 __attribute__((ext_vector_type(4)));
typedef float    f32x4 __attribute__((ext_vector_type(4)));

__device__ __forceinline__ f32x4 mfma16(f16x8 a, f16x8 b, f32x4 c) {
  return __builtin_amdgcn_mfma_f32_16x16x32_f16(a, b, c, 0, 0, 0);
}
__device__ __forceinline__ float inorm_coef(float ss) {
  return INORM_SCALE * sqrtf(247808.0f / (ss + 1e-5f));
}

// raw barrier: flush LDS writes, do NOT drain vmcnt (prefetches stay in flight)
#define BARRIER() do { asm volatile("s_waitcnt lgkmcnt(0)" ::: "memory"); \
                       __builtin_amdgcn_s_barrier();                      \
                       asm volatile("" ::: "memory"); } while (0)

// Fragment-major layouts (wave-contiguous MFMA loads, 1KB per load inst):
//  P (Q/K proj): tile (lt = l>>4, es = k>>5) of 512 f16; elem (l,k) at
//    ((z*NLT + lt)*4 + es)*512 + ((k>>3)&3)*128 + (l&15)*8 + (k&7)
//  V: tile (dt = d>>4, kt = k>>5): ((z*32 + dt)*NKT + kt)*512 + same inner
//  W: tile (nt = r>>4, kt = c>>5): (nt*16 + kt)*512 + same inner
__device__ __forceinline__ size_t vfrag_addr(size_t z, int nkt, int d, int k) {
  return (((z * 32 + (d >> 4)) * (size_t)nkt + (k >> 5)) << 9)
         + (((k >> 3) & 3) << 7) + ((d & 15) << 3) + (k & 7);
}

// ---------------- tiny kernels ----------------
__global__ void init_zero_kernel(float* __restrict__ ss) { ss[threadIdx.x] = 0.0f; }

__global__ void peT_kernel(float* __restrict__ peT) {
  const int c = blockIdx.x;                  // 0..511
  const int cc = (c < 256) ? c : c - 256;
  const float invf = 1.0f / powf(10000.0f, (float)(2 * cc) * (1.0f / 512.0f));
  for (int p = threadIdx.x; p < HWSZ; p += blockDim.x) {
    const float ang = (float)(p + 1) * invf;
    peT[c * HWSZ + p] = (c < 256) ? sinf(ang) : cosf(ang);
  }
}

// label[(i,b,p)] -> labT[b][i*484+p], padded with zeros to LKPAD
__global__ void build_labelT_kernel(const float* __restrict__ lab, float* __restrict__ labT) {
  const int g = blockIdx.x;
  if (g < 48) {
    const int im = g >> 4, b = g & 15;
    for (int p = threadIdx.x; p < HWSZ; p += blockDim.x)
      labT[(size_t)b * LKPAD + im * HWSZ + p] = lab[((size_t)im * BATCH + b) * HWSZ + p];
  } else {
    const int b = g - 48;
    for (int p = LENC + threadIdx.x; p < LKPAD; p += blockDim.x)
      labT[(size_t)b * LKPAD + p] = 0.0f;
  }
}

// W f32 [128][512] -> fragment-major f16
__global__ void cvt16_kernel(const float* __restrict__ s, f16* __restrict__ d) {
  const int i = (blockIdx.x * 256 + threadIdx.x) * 4;
  const int r = i >> 9, c = i & 511;
  const float4 v = *(const float4*)(s + i);
  f16x4 h; h[0] = (f16)v.x; h[1] = (f16)v.y; h[2] = (f16)v.z; h[3] = (f16)v.w;
  f16* dp = d + ((((size_t)(r >> 4) << 4) + (c >> 5)) << 9)
              + (((c >> 3) & 3) << 7) + ((r & 15) << 3) + (c & 7);
  *(f16x4*)dp = h;
}

// zero pad cols [LENC, LKPAD) of fragment-major V [16 z][512 d][LKPAD k]
__global__ void vpad_kernel(f16* __restrict__ vt) {
  const int d = blockIdx.x, b = blockIdx.y;
  const int k = LENC + threadIdx.x;
  if (k < LKPAD) vt[vfrag_addr(b, 48, d, k)] = (f16)0.f;
}

// feat + 1e-3*pe -> xout f32 [(im*484+p)][b][512]  AND  vt fragment-major f16
// zmul path (decoder): also zero-fills pad cols [484, 512)
__global__ __launch_bounds__(256) void build_input_kernel(
    const float* __restrict__ trainf, const float* __restrict__ testf,
    const float* __restrict__ peT, int i0, float* __restrict__ xout,
    f16* __restrict__ vt, int zmul, int col_im_step, int nkt)
{
  __shared__ float tile[32][33];
  const int tx = threadIdx.x, ty = threadIdx.y;   // 32 x 8
  const int pt = blockIdx.x * 32, ct = blockIdx.y * 32;
  const int im = blockIdx.z >> 4, b = blockIdx.z & 15;
  const int g = i0 + im;
  const float* src = (g < 3 ? trainf + (size_t)g * IMG_ELEMS
                            : testf + (size_t)(g - 3) * IMG_ELEMS)
                     + (size_t)b * (512 * 484);
  const int zv = zmul ? (im * 16 + b) : b;
  const int col0 = im * col_im_step;
#pragma unroll
  for (int j = 0; j < 4; ++j) {
    const int c = ct + ty + 8 * j, p = pt + tx;
    const int k = col0 + p;
    float val = 0.0f;
    if (p < HWSZ) {
      val = src[(size_t)c * 484 + p] + 1e-3f * peT[(size_t)c * 484 + p];
      vt[vfrag_addr(zv, nkt, c, k)] = (f16)val;
    } else if (zmul) {
      vt[vfrag_addr(zv, nkt, c, k)] = (f16)0.f;
    }
    tile[ty + 8 * j][tx] = val;               // tile[c_loc][p_loc]
  }
  __syncthreads();
#pragma unroll
  for (int j = 0; j < 4; ++j) {
    const int p = pt + ty + 8 * j, c = ct + tx;
    if (p < HWSZ)
      xout[(((size_t)im * HWSZ + p) * BATCH + b) * DMODEL + c] = tile[tx][ty + 8 * j];
  }
}

// memory (xenc, unnormalized) * cf -> Vt_mem fragment-major (zero pad via cf path)
__global__ __launch_bounds__(256) void v16t_mem_kernel(
    const float* __restrict__ src, const float* __restrict__ ssE, f16* __restrict__ dst)
{
  __shared__ f16 tile[32][33];
  const int tx = threadIdx.x, ty = threadIdx.y;
  const int l0 = blockIdx.x * 32, d0 = blockIdx.y * 32;
  const int b = blockIdx.z;
#pragma unroll
  for (int j = 0; j < 4; ++j) {
    const int l = l0 + ty + 8 * j;
    float v = 0.0f;
    if (l < LENC) {
      const float cf = inorm_coef(ssE[(l / 484) * 16 + b]);
      v = cf * src[((size_t)l * BATCH + b) * DMODEL + d0 + tx];
    }
    tile[ty + 8 * j][tx] = (f16)v;            // tile[l_loc][d_loc]
  }
  __syncthreads();
#pragma unroll
  for (int j = 0; j < 4; ++j) {
    const int d = d0 + ty + 8 * j, l = l0 + tx;
    if (l < LKPAD) dst[vfrag_addr(b, 48, d, l)] = tile[tx][ty + 8 * j];
  }
}

// ---------------- projection via MFMA + optional group scale + L2-normalize + sqrt(30) ----
// X: [M][512] f32 rows=((im*L+l)*16+b); W fragment-major; P16 out fragment-major (NLT l-tiles)
__global__ __launch_bounds__(256) void proj_mfma_kernel(
    const float* __restrict__ X, const f16* __restrict__ W16,
    const float* __restrict__ bias, const float* __restrict__ ssg,
    f16* __restrict__ P16, int L, int NLT)
{
  __shared__ f16 Xs[64][72];
  const int t = threadIdx.x;
  const int wave = t >> 6, lane = t & 63, quad = lane >> 4, ln = lane & 15;
  const int lane8 = lane * 8;
  const size_t row0 = (size_t)blockIdx.x * 64;

  f32x4 acc[8];
#pragma unroll
  for (int nt = 0; nt < 8; ++nt) acc[nt] = (f32x4){0.f, 0.f, 0.f, 0.f};

  // staging map: 4 lanes per row, 64B contiguous each (16 segments/wave, not 64)
  const int sr = t >> 2, sko = (t & 3) * 16;
  const size_t rowg = row0 + sr;
  float cf = 1.0f;
  if (ssg) {
    const int bb = (int)(rowg & 15);
    const int gg = (int)((rowg >> 4) / 484);
    cf = inorm_coef(ssg[gg * 16 + bb]);
  }
  const float* xp = X + rowg * 512 + sko;

  for (int k0 = 0; k0 < 512; k0 += 64) {
    {
      const float4 a0 = *(const float4*)(xp + k0);
      const float4 a1 = *(const float4*)(xp + k0 + 4);
      const float4 a2 = *(const float4*)(xp + k0 + 8);
      const float4 a3 = *(const float4*)(xp + k0 + 12);
      f16x8 h0, h1;
      h0[0]=(f16)(cf*a0.x); h0[1]=(f16)(cf*a0.y); h0[2]=(f16)(cf*a0.z); h0[3]=(f16)(cf*a0.w);
      h0[4]=(f16)(cf*a1.x); h0[5]=(f16)(cf*a1.y); h0[6]=(f16)(cf*a1.z); h0[7]=(f16)(cf*a1.w);
      h1[0]=(f16)(cf*a2.x); h1[1]=(f16)(cf*a2.y); h1[2]=(f16)(cf*a2.z); h1[3]=(f16)(cf*a2.w);
      h1[4]=(f16)(cf*a3.x); h1[5]=(f16)(cf*a3.y); h1[6]=(f16)(cf*a3.z); h1[7]=(f16)(cf*a3.w);
      *(f16x8*)&Xs[sr][sko]     = h0;
      *(f16x8*)&Xs[sr][sko + 8] = h1;
    }
    __syncthreads();
#pragma unroll
    for (int ks = 0; ks < 2; ++ks) {
      const f16x8 a = *(const f16x8*)&Xs[wave * 16 + ln][ks * 32 + quad * 8];
      const int kt = (k0 >> 5) + ks;
#pragma unroll
      for (int nt = 0; nt < 8; ++nt) {
        const f16x8 bf = *(const f16x8*)(W16 + (((size_t)(nt * 16 + kt)) << 9) + lane8);
        acc[nt] = mfma16(a, bf, acc[nt]);
      }
    }
    __syncthreads();
  }

  float bj[8];
#pragma unroll
  for (int nt = 0; nt < 8; ++nt) bj[nt] = bias[nt * 16 + ln];

  float y[8][4]; float ssq[4] = {0.f, 0.f, 0.f, 0.f};
#pragma unroll
  for (int nt = 0; nt < 8; ++nt)
#pragma unroll
    for (int r = 0; r < 4; ++r) {
      const float v = acc[nt][r] + bj[nt];
      y[nt][r] = v; ssq[r] = fmaf(v, v, ssq[r]);
    }
#pragma unroll
  for (int r = 0; r < 4; ++r) {
    ssq[r] += __shfl_xor(ssq[r], 1); ssq[r] += __shfl_xor(ssq[r], 2);
    ssq[r] += __shfl_xor(ssq[r], 4); ssq[r] += __shfl_xor(ssq[r], 8);
  }
#pragma unroll
  for (int r = 0; r < 4; ++r) {
    const float inv = SQRT_TEMP / fmaxf(sqrtf(ssq[r]), 1e-12f);
    const size_t rg = row0 + (size_t)wave * 16 + quad * 4 + r;
    const int b = (int)(rg & 15);
    const size_t lg = rg >> 4;
    const int im = (int)(lg / (size_t)L);
    const int l  = (int)(lg - (size_t)im * L);
    // fragment-major P write: elem (l, col = nt*16+ln)
    f16* zb = P16 + (((size_t)(im * 16 + b) * NLT + (l >> 4)) << 11) + ((l & 15) << 3) + (ln & 7);
#pragma unroll
    for (int nt = 0; nt < 8; ++nt)
      zb[((size_t)(nt >> 1) << 9) + (((nt * 2 + (ln >> 3)) & 3) << 7)] = (f16)(y[nt][r] * inv);
  }
}

// ---------------- fused flash attention v9 (single-barrier pipelined phases) ----------------
// 64q x 512d per block (8 waves), 128-key chunks, fragment-major operands.
// ONE barrier per chunk. Phase(i) = { softmax(i) from Ssm[buf]  (VALU pipe)
//                                   ∥ PV(i-1) from Psm[buf^1]   (MFMA pipe)
//                                   ∥ QK(i+1) -> Ssm[buf^1]     (MFMA pipe) }
// Ssm/Psm/ash double-buffered; bv registers WAR-recycled per ks inside PV.
// Key-masking only under block-uniform last-chunk branch; setprio on MFMA.
template<int CROSS>
__global__ __launch_bounds__(512) void attn9_kernel(
    const f16* __restrict__ pq, const f16* __restrict__ pk, const f16* __restrict__ Vt,
    const float* __restrict__ labT, float* __restrict__ X, float* __restrict__ Vout,
    const float* __restrict__ ssIn, float* __restrict__ ssO,
    float* __restrict__ ssV_, float* __restrict__ ssUV_,
    int Lq, int Lk, int nqb, int nltq, int nltk, int nktv, int pk_shared, int vt_shared)
{
  __shared__ float Ssm[2][64][132];   // 67.6 KB
  __shared__ f16   Psm[2][64][136];   // 34.8 KB
  __shared__ float msh[64], lsh[64], ash[2][64], mask_sh[64];

  const int t = threadIdx.x;
  const int wave = t >> 6, lane = t & 63, quad = lane >> 4, ln = lane & 15;
  const int lane8 = lane * 8;

  const int id = blockIdx.x;
  const int b  = (id & 7) + 8 * ((id >> 3) & 1);
  const int jj = id >> 4;
  const int qb = jj % nqb, im = jj / nqb;
  const int q0 = qb * 64;
  const int zq = im * 16 + b;
  const int zk = pk_shared ? b : zq;
  const int zv = vt_shared ? b : zq;

  const f16* pqz = pq + (((size_t)zq * nltq) << 11);
  const f16* pkz = pk + (((size_t)zk * nltk) << 11);
  const f16* Vw  = Vt + ((((size_t)zv * 32 + wave * 4) * (size_t)nktv) << 9) + lane8;
  const float* ksb = CROSS ? labT + (size_t)b * LKPAD : (const float*)0;

  // hoisted Q fragments (padded buffers: no clamp)
  f16x8 qf[4][4];
#pragma unroll
  for (int mt = 0; mt < 4; ++mt) {
    const f16* qp = pqz + (((size_t)((q0 >> 4) + mt)) << 11) + lane8;
#pragma unroll
    for (int es = 0; es < 4; ++es) qf[mt][es] = *(const f16x8*)(qp + es * 512);
  }
  // K(0)
  f16x8 kf[4];
  {
    const f16* kp = pkz + (((size_t)wave) << 11) + lane8;
#pragma unroll
    for (int es = 0; es < 4; ++es) kf[es] = *(const f16x8*)(kp + es * 512);
  }

  f32x4 oacc[4][4];
#pragma unroll
  for (int mt = 0; mt < 4; ++mt)
#pragma unroll
    for (int nt = 0; nt < 4; ++nt) oacc[mt][nt] = (f32x4){0.f, 0.f, 0.f, 0.f};

  if (t < 64) { msh[t] = NEGBIG; lsh[t] = 0.f; }
  float msum = 0.f;
  const int qs = t >> 3, cs = t & 7;

  const int nch = (Lk + 127) >> 7;

  // ---- prologue: QK(0) -> Ssm[0]; then K(1) ----
  {
    f32x4 s[4];
#pragma unroll
    for (int mt = 0; mt < 4; ++mt) s[mt] = (f32x4){0.f,0.f,0.f,0.f};
    __builtin_amdgcn_s_setprio(1);
#pragma unroll
    for (int es = 0; es < 4; ++es)
#pragma unroll
      for (int mt = 0; mt < 4; ++mt)
        s[mt] = mfma16(qf[mt][es], kf[es], s[mt]);
    __builtin_amdgcn_s_setprio(0);
#pragma unroll
    for (int mt = 0; mt < 4; ++mt)
#pragma unroll
      for (int r = 0; r < 4; ++r)
        Ssm[0][mt * 16 + quad * 4 + r][wave * 16 + ln] = s[mt][r];
  }
  if (nch > 1) {
    const f16* kp = pkz + (((size_t)(8 + wave)) << 11) + lane8;
#pragma unroll
    for (int es = 0; es < 4; ++es) kf[es] = *(const f16x8*)(kp + es * 512);
  }
  f16x8 bvA[4], bvB[4], bvC[4], bvD[4];
  BARRIER();

  for (int i = 0; i < nch; ++i) {
    const int buf = i & 1;
    const int k0 = i << 7;
    const int ktb = i << 2;
    // ---- softmax source reads issue early (latency hidden under MFMA below) ----
    f32x4 sa[4];
#pragma unroll
    for (int ii = 0; ii < 4; ++ii) sa[ii] = *(const f32x4*)&Ssm[buf][qs][cs * 16 + ii * 4];
    float4 lv[4];
    if (CROSS) {
      const float* lp = ksb + k0 + cs * 16;
#pragma unroll
      for (int ii = 0; ii < 4; ++ii) lv[ii] = *(const float4*)(lp + ii * 4);
    }
    // ---- PV(i-1) with WAR-recycled V loads (bv[ks] <- V(i).ks after use) ----
    if (i) {
#pragma unroll
      for (int mt = 0; mt < 4; ++mt) {
        f32x4 al;
#pragma unroll
        for (int r = 0; r < 4; ++r) al[r] = ash[buf ^ 1][mt * 16 + quad * 4 + r];
#pragma unroll
        for (int nt = 0; nt < 4; ++nt) oacc[mt][nt] *= al;
      }
      f16x8 pa[4];
      // ks = 0
#pragma unroll
      for (int mt = 0; mt < 4; ++mt) pa[mt] = *(const f16x8*)&Psm[buf ^ 1][mt * 16 + ln][quad * 8];
      __builtin_amdgcn_s_setprio(1);
#pragma unroll
      for (int nt = 0; nt < 4; ++nt)
#pragma unroll
        for (int mt = 0; mt < 4; ++mt)
          oacc[mt][nt] = mfma16(pa[mt], bvA[nt], oacc[mt][nt]);
      __builtin_amdgcn_s_setprio(0);
#pragma unroll
      for (int nt = 0; nt < 4; ++nt)
        bvA[nt] = *(const f16x8*)(Vw + (((size_t)(nt * nktv + ktb)) << 9));
      // ks = 1
#pragma unroll
      for (int mt = 0; mt < 4; ++mt) pa[mt] = *(const f16x8*)&Psm[buf ^ 1][mt * 16 + ln][32 + quad * 8];
      __builtin_amdgcn_s_setprio(1);
#pragma unroll
      for (int nt = 0; nt < 4; ++nt)
#pragma unroll
        for (int mt = 0; mt < 4; ++mt)
          oacc[mt][nt] = mfma16(pa[mt], bvB[nt], oacc[mt][nt]);
      __builtin_amdgcn_s_setprio(0);
#pragma unroll
      for (int nt = 0; nt < 4; ++nt)
        bvB[nt] = *(const f16x8*)(Vw + (((size_t)(nt * nktv + ktb + 1)) << 9));
      // ks = 2
#pragma unroll
      for (int mt = 0; mt < 4; ++mt) pa[mt] = *(const f16x8*)&Psm[buf ^ 1][mt * 16 + ln][64 + quad * 8];
      __builtin_amdgcn_s_setprio(1);
#pragma unroll
      for (int nt = 0; nt < 4; ++nt)
#pragma unroll
        for (int mt = 0; mt < 4; ++mt)
          oacc[mt][nt] = mfma16(pa[mt], bvC[nt], oacc[mt][nt]);
      __builtin_amdgcn_s_setprio(0);
#pragma unroll
      for (int nt = 0; nt < 4; ++nt)
        bvC[nt] = *(const f16x8*)(Vw + (((size_t)(nt * nktv + ktb + 2)) << 9));
      // ks = 3
#pragma unroll
      for (int mt = 0; mt < 4; ++mt) pa[mt] = *(const f16x8*)&Psm[buf ^ 1][mt * 16 + ln][96 + quad * 8];
      __builtin_amdgcn_s_setprio(1);
#pragma unroll
      for (int nt = 0; nt < 4; ++nt)
#pragma unroll
        for (int mt = 0; mt < 4; ++mt)
          oacc[mt][nt] = mfma16(pa[mt], bvD[nt], oacc[mt][nt]);
      __builtin_amdgcn_s_setprio(0);
#pragma unroll
      for (int nt = 0; nt < 4; ++nt)
        bvD[nt] = *(const f16x8*)(Vw + (((size_t)(nt * nktv + ktb + 3)) << 9));
    } else {
      // first phase: just load V(0)
#pragma unroll
      for (int nt = 0; nt < 4; ++nt) {
        const f16* vpn = Vw + (((size_t)(nt * nktv)) << 9);
        bvA[nt] = *(const f16x8*)(vpn);
        bvB[nt] = *(const f16x8*)(vpn + 512);
        bvC[nt] = *(const f16x8*)(vpn + 1024);
        bvD[nt] = *(const f16x8*)(vpn + 1536);
      }
    }
    // ---- QK(i+1) -> Ssm[buf^1]; then K(i+2) ----
    if (i + 1 < nch) {
      f32x4 s[4];
#pragma unroll
      for (int mt = 0; mt < 4; ++mt) s[mt] = (f32x4){0.f,0.f,0.f,0.f};
      __builtin_amdgcn_s_setprio(1);
#pragma unroll
      for (int es = 0; es < 4; ++es)
#pragma unroll
        for (int mt = 0; mt < 4; ++mt)
          s[mt] = mfma16(qf[mt][es], kf[es], s[mt]);
      __builtin_amdgcn_s_setprio(0);
#pragma unroll
      for (int mt = 0; mt < 4; ++mt)
#pragma unroll
        for (int r = 0; r < 4; ++r)
          Ssm[buf ^ 1][mt * 16 + quad * 4 + r][wave * 16 + ln] = s[mt][r];
      if (i + 2 < nch) {
        const f16* kp = pkz + (((size_t)(((i + 2) << 3) + wave)) << 11) + lane8;
#pragma unroll
        for (int es = 0; es < 4; ++es) kf[es] = *(const f16x8*)(kp + es * 512);
      }
    }
    // ---- softmax(i): thread (qs, cs) owns 16 keys of q-row qs ----
    {
      float sv[16];
#pragma unroll
      for (int ii = 0; ii < 4; ++ii)
#pragma unroll
        for (int j = 0; j < 4; ++j)
          sv[ii * 4 + j] = sa[ii][j];
      if (k0 + 128 > Lk) {                    // block-uniform: last partial chunk only
        const int kb = k0 + cs * 16;
#pragma unroll
        for (int j = 0; j < 16; ++j)
          if (kb + j >= Lk) sv[j] = NEGBIG;
      }
      float m8[8];
#pragma unroll
      for (int j = 0; j < 8; ++j) m8[j] = fmaxf(sv[j], sv[j + 8]);
      float m4[4];
#pragma unroll
      for (int j = 0; j < 4; ++j) m4[j] = fmaxf(m8[j], m8[j + 4]);
      float mx = fmaxf(fmaxf(m4[0], m4[2]), fmaxf(m4[1], m4[3]));
      mx = fmaxf(mx, __shfl_xor(mx, 1));
      mx = fmaxf(mx, __shfl_xor(mx, 2));
      mx = fmaxf(mx, __shfl_xor(mx, 4));
      const float mold = msh[qs];
      const float mnew = fmaxf(mold, mx);
      const float alpha = __expf(mold - mnew);
      float ps = 0.f, pm = 0.f;
      f16x8 pv0, pv1;
#pragma unroll
      for (int j = 0; j < 16; ++j) {
        float p = __expf(sv[j] - mnew);
        ps += p;
        if (CROSS) p *= lv[j >> 2][j & 3];
        pm += p;
        if (j < 8) pv0[j] = (f16)p; else pv1[j - 8] = (f16)p;
      }
      *(f16x8*)&Psm[buf][qs][cs * 16]     = pv0;
      *(f16x8*)&Psm[buf][qs][cs * 16 + 8] = pv1;
      ps += __shfl_xor(ps, 1); ps += __shfl_xor(ps, 2); ps += __shfl_xor(ps, 4);
      msum = msum * alpha + pm;
      if (cs == 0) { msh[qs] = mnew; lsh[qs] = lsh[qs] * alpha + ps; ash[buf][qs] = alpha; }
    }
    BARRIER();
  }

  // ---- final PV(nch-1) ----
  {
    const int bl = (nch - 1) & 1;
#pragma unroll
    for (int mt = 0; mt < 4; ++mt) {
      f32x4 al;
#pragma unroll
      for (int r = 0; r < 4; ++r) al[r] = ash[bl][mt * 16 + quad * 4 + r];
#pragma unroll
      for (int nt = 0; nt < 4; ++nt) oacc[mt][nt] *= al;
    }
    f16x8 pa[4];
#pragma unroll
    for (int ks = 0; ks < 4; ++ks) {
#pragma unroll
      for (int mt = 0; mt < 4; ++mt) pa[mt] = *(const f16x8*)&Psm[bl][mt * 16 + ln][ks * 32 + quad * 8];
      __builtin_amdgcn_s_setprio(1);
#pragma unroll
      for (int nt = 0; nt < 4; ++nt) {
        const f16x8 bv = (ks == 0) ? bvA[nt] : (ks == 1) ? bvB[nt] : (ks == 2) ? bvC[nt] : bvD[nt];
#pragma unroll
        for (int mt = 0; mt < 4; ++mt)
          oacc[mt][nt] = mfma16(pa[mt], bv, oacc[mt][nt]);
      }
      __builtin_amdgcn_s_setprio(0);
    }
  }

  // ---- epilogue ----
  if (CROSS) {
    float ms = msum;
    ms += __shfl_xor(ms, 1); ms += __shfl_xor(ms, 2); ms += __shfl_xor(ms, 4);
    if (cs == 0) mask_sh[qs] = ms / lsh[qs];
    __syncthreads();
  }

  const int g0  = (im * Lq + q0) / 484;
  const int bhi = (g0 + 1) * 484 - im * Lq;             // local-q group boundary
  const bool strad = (!CROSS) && (bhi < Lq) && (bhi < q0 + 64);

  float a0 = 0.f, a1 = 0.f, a2 = 0.f;
  const float cfA = CROSS ? inorm_coef(ssIn[im * 16 + b]) : 0.f;

#pragma unroll
  for (int mt = 0; mt < 4; ++mt) {
    f32x4 li;
#pragma unroll
    for (int r = 0; r < 4; ++r) li[r] = 1.0f / lsh[mt * 16 + quad * 4 + r];
#pragma unroll
    for (int r = 0; r < 4; ++r) {
      const int q = q0 + mt * 16 + quad * 4 + r;
      if (q < Lq) {
        const size_t base = (((size_t)(im * Lq + q)) * BATCH + b) * DMODEL + wave * 64 + ln;
        if (!CROSS) {
          const bool hi = (q >= bhi);
#pragma unroll
          for (int nt = 0; nt < 4; ++nt) {
            const float y = X[base + nt * 16] + oacc[mt][nt][r] * li[r];
            X[base + nt * 16] = y;
            if (hi) a1 += y * y; else a0 += y * y;
          }
        } else {
          const float mval = mask_sh[mt * 16 + quad * 4 + r];
#pragma unroll
          for (int nt = 0; nt < 4; ++nt) {
            const float x1 = cfA * X[base + nt * 16];
            const float u = x1 * mval;
            const float v = x1 + oacc[mt][nt][r] * li[r];
            X[base + nt * 16] = u;
            Vout[base + nt * 16] = v;
            a0 += u * u; a1 += v * v; a2 += u * v;
          }
        }
      }
    }
  }
#pragma unroll
  for (int m = 32; m; m >>= 1) {
    a0 += __shfl_xor(a0, m); a1 += __shfl_xor(a1, m);
    if (CROSS) a2 += __shfl_xor(a2, m);
  }
  if (lane == 0) {
    if (!CROSS) {
      atomicAdd(ssO + g0 * 16 + b, a0);
      if (strad) atomicAdd(ssO + (g0 + 1) * 16 + b, a1);
    } else {
      const int g = im * 16 + b;
      atomicAdd(ssO + g, a0);
      atomicAdd(ssV_ + g, a1);
      atomicAdd(ssUV_ + g, a2);
    }
  }
}

// cu*cz, cv*cz per group (exact ssZ expansion)
__global__ void coef_final_kernel(const float* __restrict__ ssU, const float* __restrict__ ssV,
                                  const float* __restrict__ ssUV, float* __restrict__ AB, int n)
{
  const int t = threadIdx.x;
  if (t < n) {
    const float su = ssU[t], sv = ssV[t], suv = ssUV[t];
    const float cu = inorm_coef(su), cv = inorm_coef(sv);
    const float ssz = cu * cu * su + cv * cv * sv + 2.f * cu * cv * suv;
    const float cz = inorm_coef(ssz);
    AB[2 * t] = cu * cz; AB[2 * t + 1] = cv * cz;
  }
}

// out[b][c][p] = A*u[(im,p,b,c)] + B*v[...]  (fused final mix + inorm + transpose)
__global__ __launch_bounds__(256) void final_out_kernel(
    const float* __restrict__ u, const float* __restrict__ v,
    const float* __restrict__ AB, float* __restrict__ out, int i0)
{
  __shared__ float tile[32][33];
  const int tx = threadIdx.x, ty = threadIdx.y;
  const int pt = blockIdx.x * 32, ct = blockIdx.y * 32;
  const int z = blockIdx.z;
  const int im = z >> 4, b = z & 15;
  const float A = AB[2 * z], B = AB[2 * z + 1];
#pragma unroll
  for (int j = 0; j < 4; ++j) {
    const int p = pt + ty + 8 * j, c = ct + tx;
    float val = 0.0f;
    if (p < HWSZ) {
      const size_t idx = (((size_t)im * HWSZ + p) * BATCH + b) * DMODEL + c;
      val = A * u[idx] + B * v[idx];
    }
    tile[ty + 8 * j][tx] = val;               // tile[p_loc][c_loc]
  }
  __syncthreads();
  const int g = i0 + im;
  const size_t base = (g < 3 ? 0ull : ENC_OUT)
                    + ((size_t)(((g < 3 ? g : g - 3) * 16 + b) * 512)) * 484ull;
#pragma unroll
  for (int j = 0; j < 4; ++j) {
    const int c = ct + ty + 8 * j, p = pt + tx;
    if (p < HWSZ) out[base + (size_t)c * 484 + p] = tile[tx][ty + 8 * j];
  }
}

// ---------------- host orchestration ----------------
extern "C" void kernel_launch(void* const* d_in, const int* in_sizes, int n_in,
                              void* d_out, int out_size, void* d_ws, size_t ws_size,
                              hipStream_t stream) {
  (void)in_sizes; (void)n_in; (void)out_size;
  const float* train_feat  = (const float*)d_in[0];
  const float* test_feat   = (const float*)d_in[1];
  const float* train_label = (const float*)d_in[2];
  const float* wk_self     = (const float*)d_in[3];
  const float* bk_self     = (const float*)d_in[4];
  const float* wk_cross    = (const float*)d_in[5];
  const float* bk_cross    = (const float*)d_in[6];
  float* out = (float*)d_out;
  char* wsb  = (char*)d_ws;

  size_t off = 0;
  auto alloc = [&](size_t bytes) { size_t r = off; off = (r + bytes + 255) & ~(size_t)255; return r; };
  const size_t o_peT   = alloc(991232ull);             // [512][484] f32
  const size_t o_labT  = alloc(16ull * LKPAD * 4);
  const size_t o_ss    = alloc(4096);                  // ssE@0 ssA@128 ssU@256 ssV@384 ssUV@512 AB@640
  const size_t o_w16s  = alloc(131072);
  const size_t o_w16c  = alloc(131072);
  const size_t o_xenc  = alloc(47579136ull);           // [1452][16][512] f32
  const size_t o_p16   = alloc(6291456ull);            // 16 z x 96 tiles x 4 es x 512 f16
  const size_t o_vte   = alloc(16ull*512*LKPAD*2);     // Vt_enc fragment-major
  const size_t o_vtm   = alloc(16ull*512*LKPAD*2);     // Vt_mem fragment-major
  const size_t fixed = off;

  float* peT  = (float*)(wsb + o_peT);
  float* labT = (float*)(wsb + o_labT);
  float* ss   = (float*)(wsb + o_ss);
  f16*   w16s = (f16*)(wsb + o_w16s);
  f16*   w16c = (f16*)(wsb + o_w16c);
  float* xenc = (float*)(wsb + o_xenc);
  f16*   p16  = (f16*)(wsb + o_p16);
  f16*   vte  = (f16*)(wsb + o_vte);
  f16*   vtm  = (f16*)(wsb + o_vtm);
  float* ssE = ss, *ssA = ss + 128, *ssU = ss + 256, *ssV = ss + 384, *ssUV = ss + 512;
  float* AB  = ss + 640;

  // per image: xd + vbuf (f32) + pq16d (16 z x 32x4x512 f16) + vtd (16 z x 32x16x512 f16)
  const size_t decPer = 15859712ull * 2 + 2097152ull + 8388608ull;
  int NB = 6;
  if (fixed + (size_t)NB * decPer + 4096 > ws_size) NB = 3;
  if (fixed + (size_t)NB * decPer + 4096 > ws_size) NB = 1;

  float* xd    = (float*)(wsb + fixed);
  float* vbuf  = xd + (size_t)NB * IMG_ELEMS;
  f16*   pq16d = (f16*)(vbuf + (size_t)NB * IMG_ELEMS);
  f16*   vtd   = pq16d + (size_t)NB * 1048576ull;

  // ---- prep ----
  init_zero_kernel<<<dim3(1), dim3(1024), 0, stream>>>(ss);
  peT_kernel<<<dim3(512), dim3(256), 0, stream>>>(peT);
  build_labelT_kernel<<<dim3(64), dim3(256), 0, stream>>>(train_label, labT);
  cvt16_kernel<<<dim3(64), dim3(256), 0, stream>>>(wk_self, w16s);
  cvt16_kernel<<<dim3(64), dim3(256), 0, stream>>>(wk_cross, w16c);
  vpad_kernel<<<dim3(512, 16), dim3(96), 0, stream>>>(vte);

  // ---- encoder ----
  build_input_kernel<<<dim3(16, 16, 48), dim3(32, 8), 0, stream>>>(
      train_feat, test_feat, peT, 0, xenc, vte, /*zmul=*/0, /*col_im_step=*/484, /*nkt=*/48);
  proj_mfma_kernel<<<dim3(363), dim3(256), 0, stream>>>(xenc, w16s, bk_self, (const float*)0, p16, LENC, 96);
  attn9_kernel<0><<<dim3(23 * 16), dim3(512), 0, stream>>>(
      p16, p16, vte, (const float*)0, xenc, (float*)0, (const float*)0,
      ssE, (float*)0, (float*)0, LENC, LENC, 23, 96, 96, 48, 0, 0);
  proj_mfma_kernel<<<dim3(363), dim3(256), 0, stream>>>(xenc, w16c, bk_cross, ssE, p16, LENC, 96); // pkc
  v16t_mem_kernel<<<dim3(48, 16, 16), dim3(32, 8), 0, stream>>>(xenc, ssE, vtm);

  // ---- decoders (NB images per batch) ----
  for (int i0 = 0; i0 < 6; i0 += NB) {
    build_input_kernel<<<dim3(16, 16, NB * 16), dim3(32, 8), 0, stream>>>(
        train_feat, test_feat, peT, i0, xd, vtd, /*zmul=*/1, /*col_im_step=*/0, /*nkt=*/16);
    // self-attention (+residual+ssA fused)
    proj_mfma_kernel<<<dim3(NB * 121), dim3(256), 0, stream>>>(xd, w16s, bk_self, (const float*)0, pq16d, HWSZ, 32);
    attn9_kernel<0><<<dim3(8 * 16 * NB), dim3(512), 0, stream>>>(
        pq16d, pq16d, vtd, (const float*)0, xd, (float*)0, (const float*)0,
        ssA + i0 * 16, (float*)0, (float*)0, HWSZ, HWSZ, 8, 32, 32, 16, 0, 0);
    // cross-attention (mask/u/v/ssU/ssV/ssUV fused)
    proj_mfma_kernel<<<dim3(NB * 121), dim3(256), 0, stream>>>(xd, w16c, bk_cross, ssA + i0 * 16, pq16d, HWSZ, 32);
    attn9_kernel<1><<<dim3(8 * 16 * NB), dim3(512), 0, stream>>>(
        pq16d, p16 /*pkc*/, vtm, labT, xd, vbuf, ssA + i0 * 16,
        ssU + i0 * 16, ssV + i0 * 16, ssUV + i0 * 16, HWSZ, LENC, 8, 32, 96, 48, 1, 1);
    coef_final_kernel<<<dim3(1), dim3(128), 0, stream>>>(
        ssU + i0 * 16, ssV + i0 * 16, ssUV + i0 * 16, AB + i0 * 32, NB * 16);
    final_out_kernel<<<dim3(16, 16, NB * 16), dim3(32, 8), 0, stream>>>(
        xd, vbuf, AB + i0 * 32, out, i0);
  }
}

// Round 7
// 894.336 us; speedup vs baseline: 1.1479x; 1.1479x over previous
//
#include <hip/hip_runtime.h>
#include <math.h>

// ---------------- problem constants ----------------
#define BATCH   16
#define DMODEL  512
#define EKEY    128
#define HWSZ    484
#define LENC    1452
#define LKPAD   1536                       // padded key length (12 x 128)
#define IMG_ELEMS (HWSZ*BATCH*DMODEL)      // 3,964,928 floats per image [484][16][512]
#define ENC_OUT   11894784ull
#define SQRT_TEMP 5.4772255750516611f      // sqrt(30) folded into both projections
#define INORM_SCALE 0.011048543456039806f  // sqrt(1/(512*16))
#define NEGBIG   -3.0e38f

typedef _Float16 f16;
typedef _Float16 f16x8 __attribute__((ext_vector_type(8)));
typedef _Float16 f16x4 __attribute__((ext_vector_type(4)));
typedef float    f32x4 __attribute__((ext_vector_type(4)));

__device__ __forceinline__ f32x4 mfma16(f16x8 a, f16x8 b, f32x4 c) {
  return __builtin_amdgcn_mfma_f32_16x16x32_f16(a, b, c, 0, 0, 0);
}
__device__ __forceinline__ float inorm_coef(float ss) {
  return INORM_SCALE * sqrtf(247808.0f / (ss + 1e-5f));
}

// raw barrier: flush LDS writes, do NOT drain vmcnt (prefetches stay in flight)
#define BARRIER() do { asm volatile("s_waitcnt lgkmcnt(0)" ::: "memory"); \
                       __builtin_amdgcn_s_barrier();                      \
                       asm volatile("" ::: "memory"); } while (0)

// Fragment-major layouts (wave-contiguous MFMA loads, 1KB per load inst):
//  P (Q/K proj): tile (lt = l>>4, es = k>>5) of 512 f16; elem (l,k) at
//    ((z*NLT + lt)*4 + es)*512 + ((k>>3)&3)*128 + (l&15)*8 + (k&7)
//  V: tile (dt = d>>4, kt = k>>5): ((z*32 + dt)*NKT + kt)*512 + same inner
//  W: tile (nt = r>>4, kt = c>>5): (nt*16 + kt)*512 + same inner
__device__ __forceinline__ size_t vfrag_addr(size_t z, int nkt, int d, int k) {
  return (((z * 32 + (d >> 4)) * (size_t)nkt + (k >> 5)) << 9)
         + (((k >> 3) & 3) << 7) + ((d & 15) << 3) + (k & 7);
}

// ---------------- tiny kernels ----------------
__global__ void init_zero_kernel(float* __restrict__ ss) { ss[threadIdx.x] = 0.0f; }

__global__ void peT_kernel(float* __restrict__ peT) {
  const int c = blockIdx.x;                  // 0..511
  const int cc = (c < 256) ? c : c - 256;
  const float invf = 1.0f / powf(10000.0f, (float)(2 * cc) * (1.0f / 512.0f));
  for (int p = threadIdx.x; p < HWSZ; p += blockDim.x) {
    const float ang = (float)(p + 1) * invf;
    peT[c * HWSZ + p] = (c < 256) ? sinf(ang) : cosf(ang);
  }
}

// label[(i,b,p)] -> labT[b][i*484+p], padded with zeros to LKPAD
__global__ void build_labelT_kernel(const float* __restrict__ lab, float* __restrict__ labT) {
  const int g = blockIdx.x;
  if (g < 48) {
    const int im = g >> 4, b = g & 15;
    for (int p = threadIdx.x; p < HWSZ; p += blockDim.x)
      labT[(size_t)b * LKPAD + im * HWSZ + p] = lab[((size_t)im * BATCH + b) * HWSZ + p];
  } else {
    const int b = g - 48;
    for (int p = LENC + threadIdx.x; p < LKPAD; p += blockDim.x)
      labT[(size_t)b * LKPAD + p] = 0.0f;
  }
}

// W f32 [128][512] -> fragment-major f16
__global__ void cvt16_kernel(const float* __restrict__ s, f16* __restrict__ d) {
  const int i = (blockIdx.x * 256 + threadIdx.x) * 4;
  const int r = i >> 9, c = i & 511;
  const float4 v = *(const float4*)(s + i);
  f16x4 h; h[0] = (f16)v.x; h[1] = (f16)v.y; h[2] = (f16)v.z; h[3] = (f16)v.w;
  f16* dp = d + ((((size_t)(r >> 4) << 4) + (c >> 5)) << 9)
              + (((c >> 3) & 3) << 7) + ((r & 15) << 3) + (c & 7);
  *(f16x4*)dp = h;
}

// zero pad cols [LENC, LKPAD) of fragment-major V [16 z][512 d][LKPAD k]
__global__ void vpad_kernel(f16* __restrict__ vt) {
  const int d = blockIdx.x, b = blockIdx.y;
  const int k = LENC + threadIdx.x;
  if (k < LKPAD) vt[vfrag_addr(b, 48, d, k)] = (f16)0.f;
}

// feat + 1e-3*pe -> xout f32 [(im*484+p)][b][512]  AND  vt fragment-major f16
// zmul path (decoder): also zero-fills pad cols [484, 512)
__global__ __launch_bounds__(256) void build_input_kernel(
    const float* __restrict__ trainf, const float* __restrict__ testf,
    const float* __restrict__ peT, int i0, float* __restrict__ xout,
    f16* __restrict__ vt, int zmul, int col_im_step, int nkt)
{
  __shared__ float tile[32][33];
  const int tx = threadIdx.x, ty = threadIdx.y;   // 32 x 8
  const int pt = blockIdx.x * 32, ct = blockIdx.y * 32;
  const int im = blockIdx.z >> 4, b = blockIdx.z & 15;
  const int g = i0 + im;
  const float* src = (g < 3 ? trainf + (size_t)g * IMG_ELEMS
                            : testf + (size_t)(g - 3) * IMG_ELEMS)
                     + (size_t)b * (512 * 484);
  const int zv = zmul ? (im * 16 + b) : b;
  const int col0 = im * col_im_step;
#pragma unroll
  for (int j = 0; j < 4; ++j) {
    const int c = ct + ty + 8 * j, p = pt + tx;
    const int k = col0 + p;
    float val = 0.0f;
    if (p < HWSZ) {
      val = src[(size_t)c * 484 + p] + 1e-3f * peT[(size_t)c * 484 + p];
      vt[vfrag_addr(zv, nkt, c, k)] = (f16)val;
    } else if (zmul) {
      vt[vfrag_addr(zv, nkt, c, k)] = (f16)0.f;
    }
    tile[ty + 8 * j][tx] = val;               // tile[c_loc][p_loc]
  }
  __syncthreads();
#pragma unroll
  for (int j = 0; j < 4; ++j) {
    const int p = pt + ty + 8 * j, c = ct + tx;
    if (p < HWSZ)
      xout[(((size_t)im * HWSZ + p) * BATCH + b) * DMODEL + c] = tile[tx][ty + 8 * j];
  }
}

// memory (xenc, unnormalized) * cf -> Vt_mem fragment-major (zero pad via cf path)
__global__ __launch_bounds__(256) void v16t_mem_kernel(
    const float* __restrict__ src, const float* __restrict__ ssE, f16* __restrict__ dst)
{
  __shared__ f16 tile[32][33];
  const int tx = threadIdx.x, ty = threadIdx.y;
  const int l0 = blockIdx.x * 32, d0 = blockIdx.y * 32;
  const int b = blockIdx.z;
#pragma unroll
  for (int j = 0; j < 4; ++j) {
    const int l = l0 + ty + 8 * j;
    float v = 0.0f;
    if (l < LENC) {
      const float cf = inorm_coef(ssE[(l / 484) * 16 + b]);
      v = cf * src[((size_t)l * BATCH + b) * DMODEL + d0 + tx];
    }
    tile[ty + 8 * j][tx] = (f16)v;            // tile[l_loc][d_loc]
  }
  __syncthreads();
#pragma unroll
  for (int j = 0; j < 4; ++j) {
    const int d = d0 + ty + 8 * j, l = l0 + tx;
    if (l < LKPAD) dst[vfrag_addr(b, 48, d, l)] = tile[tx][ty + 8 * j];
  }
}

// ---------------- projection via MFMA + optional group scale + L2-normalize + sqrt(30) ----
// X: [M][512] f32 rows=((im*L+l)*16+b); W fragment-major; P16 out fragment-major (NLT l-tiles)
__global__ __launch_bounds__(256) void proj_mfma_kernel(
    const float* __restrict__ X, const f16* __restrict__ W16,
    const float* __restrict__ bias, const float* __restrict__ ssg,
    f16* __restrict__ P16, int L, int NLT)
{
  __shared__ f16 Xs[64][72];
  const int t = threadIdx.x;
  const int wave = t >> 6, lane = t & 63, quad = lane >> 4, ln = lane & 15;
  const int lane8 = lane * 8;
  const size_t row0 = (size_t)blockIdx.x * 64;

  f32x4 acc[8];
#pragma unroll
  for (int nt = 0; nt < 8; ++nt) acc[nt] = (f32x4){0.f, 0.f, 0.f, 0.f};

  // staging map: 4 lanes per row, 64B contiguous each (16 segments/wave, not 64)
  const int sr = t >> 2, sko = (t & 3) * 16;
  const size_t rowg = row0 + sr;
  float cf = 1.0f;
  if (ssg) {
    const int bb = (int)(rowg & 15);
    const int gg = (int)((rowg >> 4) / 484);
    cf = inorm_coef(ssg[gg * 16 + bb]);
  }
  const float* xp = X + rowg * 512 + sko;

  for (int k0 = 0; k0 < 512; k0 += 64) {
    {
      const float4 a0 = *(const float4*)(xp + k0);
      const float4 a1 = *(const float4*)(xp + k0 + 4);
      const float4 a2 = *(const float4*)(xp + k0 + 8);
      const float4 a3 = *(const float4*)(xp + k0 + 12);
      f16x8 h0, h1;
      h0[0]=(f16)(cf*a0.x); h0[1]=(f16)(cf*a0.y); h0[2]=(f16)(cf*a0.z); h0[3]=(f16)(cf*a0.w);
      h0[4]=(f16)(cf*a1.x); h0[5]=(f16)(cf*a1.y); h0[6]=(f16)(cf*a1.z); h0[7]=(f16)(cf*a1.w);
      h1[0]=(f16)(cf*a2.x); h1[1]=(f16)(cf*a2.y); h1[2]=(f16)(cf*a2.z); h1[3]=(f16)(cf*a2.w);
      h1[4]=(f16)(cf*a3.x); h1[5]=(f16)(cf*a3.y); h1[6]=(f16)(cf*a3.z); h1[7]=(f16)(cf*a3.w);
      *(f16x8*)&Xs[sr][sko]     = h0;
      *(f16x8*)&Xs[sr][sko + 8] = h1;
    }
    __syncthreads();
#pragma unroll
    for (int ks = 0; ks < 2; ++ks) {
      const f16x8 a = *(const f16x8*)&Xs[wave * 16 + ln][ks * 32 + quad * 8];
      const int kt = (k0 >> 5) + ks;
#pragma unroll
      for (int nt = 0; nt < 8; ++nt) {
        const f16x8 bf = *(const f16x8*)(W16 + (((size_t)(nt * 16 + kt)) << 9) + lane8);
        acc[nt] = mfma16(a, bf, acc[nt]);
      }
    }
    __syncthreads();
  }

  float bj[8];
#pragma unroll
  for (int nt = 0; nt < 8; ++nt) bj[nt] = bias[nt * 16 + ln];

  float y[8][4]; float ssq[4] = {0.f, 0.f, 0.f, 0.f};
#pragma unroll
  for (int nt = 0; nt < 8; ++nt)
#pragma unroll
    for (int r = 0; r < 4; ++r) {
      const float v = acc[nt][r] + bj[nt];
      y[nt][r] = v; ssq[r] = fmaf(v, v, ssq[r]);
    }
#pragma unroll
  for (int r = 0; r < 4; ++r) {
    ssq[r] += __shfl_xor(ssq[r], 1); ssq[r] += __shfl_xor(ssq[r], 2);
    ssq[r] += __shfl_xor(ssq[r], 4); ssq[r] += __shfl_xor(ssq[r], 8);
  }
#pragma unroll
  for (int r = 0; r < 4; ++r) {
    const float inv = SQRT_TEMP / fmaxf(sqrtf(ssq[r]), 1e-12f);
    const size_t rg = row0 + (size_t)wave * 16 + quad * 4 + r;
    const int b = (int)(rg & 15);
    const size_t lg = rg >> 4;
    const int im = (int)(lg / (size_t)L);
    const int l  = (int)(lg - (size_t)im * L);
    // fragment-major P write: elem (l, col = nt*16+ln)
    f16* zb = P16 + (((size_t)(im * 16 + b) * NLT + (l >> 4)) << 11) + ((l & 15) << 3) + (ln & 7);
#pragma unroll
    for (int nt = 0; nt < 8; ++nt)
      zb[((size_t)(nt >> 1) << 9) + (((nt * 2 + (ln >> 3)) & 3) << 7)] = (f16)(y[nt][r] * inv);
  }
}

// ---------------- fused flash attention v10 (single-barrier pipeline, Q in LDS) ----------------
// 64q x 512d per block (8 waves), 128-key chunks, fragment-major operands.
// ONE barrier per chunk. Phase(i) = { PV(i-1) from Psm[buf^1]  (MFMA)
//                                   ∥ QK(i+1) -> Ssm[buf^1]    (MFMA, Q read from LDS)
//                                   ∥ softmax(i) from Ssm[buf] (VALU) }
// Persistent regs: kf(16) + bv(64) + oacc(64 AGPR) — Q lives in LDS (16 KB) to stay
// under the 256-reg/wave ceiling (r4/r6 lesson: spills show as FETCH/WRITE bloat).
template<int CROSS>
__global__ __launch_bounds__(512) void attn10_kernel(
    const f16* __restrict__ pq, const f16* __restrict__ pk, const f16* __restrict__ Vt,
    const float* __restrict__ labT, float* __restrict__ X, float* __restrict__ Vout,
    const float* __restrict__ ssIn, float* __restrict__ ssO,
    float* __restrict__ ssV_, float* __restrict__ ssUV_,
    int Lq, int Lk, int nqb, int nltq, int nltk, int nktv, int pk_shared, int vt_shared)
{
  __shared__ float Ssm[2][64][132];   // 67.6 KB
  __shared__ f16   Psm[2][64][136];   // 34.8 KB
  __shared__ f16   Qlds[4][2048];     // 16 KB, fragment-major tiles
  __shared__ float msh[64], lsh[64], ash[2][64], mask_sh[64];

  const int t = threadIdx.x;
  const int wave = t >> 6, lane = t & 63, quad = lane >> 4, ln = lane & 15;
  const int lane8 = lane * 8;

  const int id = blockIdx.x;
  const int b  = (id & 7) + 8 * ((id >> 3) & 1);
  const int jj = id >> 4;
  const int qb = jj % nqb, im = jj / nqb;
  const int q0 = qb * 64;
  const int zq = im * 16 + b;
  const int zk = pk_shared ? b : zq;
  const int zv = vt_shared ? b : zq;

  const f16* pqz = pq + (((size_t)zq * nltq) << 11);
  const f16* pkz = pk + (((size_t)zk * nltk) << 11);
  const f16* Vw  = Vt + ((((size_t)zv * 32 + wave * 4) * (size_t)nktv) << 9) + lane8;
  const float* ksb = CROSS ? labT + (size_t)b * LKPAD : (const float*)0;

  // ---- stage Q tile into LDS (once) ----
  {
    const int mtc = t >> 7;            // 0..3
    const int jc  = (t & 127) * 16;    // 0..2032
    const f16* src = pqz + (((size_t)((q0 >> 4) + mtc)) << 11) + jc;
    *(f16x8*)&Qlds[mtc][jc]     = *(const f16x8*)(src);
    *(f16x8*)&Qlds[mtc][jc + 8] = *(const f16x8*)(src + 8);
  }
  // K(0)
  f16x8 kf[4];
  {
    const f16* kp = pkz + (((size_t)wave) << 11) + lane8;
#pragma unroll
    for (int es = 0; es < 4; ++es) kf[es] = *(const f16x8*)(kp + es * 512);
  }

  f32x4 oacc[4][4];
#pragma unroll
  for (int mt = 0; mt < 4; ++mt)
#pragma unroll
    for (int nt = 0; nt < 4; ++nt) oacc[mt][nt] = (f32x4){0.f, 0.f, 0.f, 0.f};

  if (t < 64) { msh[t] = NEGBIG; lsh[t] = 0.f; }
  float msum = 0.f;
  const int qs = t >> 3, cs = t & 7;

  const int nch = (Lk + 127) >> 7;

  BARRIER();   // Q staged

  // ---- prologue: QK(0) -> Ssm[0]; then K(1) ----
  {
    f32x4 s[4];
#pragma unroll
    for (int mt = 0; mt < 4; ++mt) s[mt] = (f32x4){0.f,0.f,0.f,0.f};
#pragma unroll
    for (int mth = 0; mth < 2; ++mth) {
      f16x8 qa[2][4];
#pragma unroll
      for (int m2 = 0; m2 < 2; ++m2)
#pragma unroll
        for (int es = 0; es < 4; ++es)
          qa[m2][es] = *(const f16x8*)&Qlds[mth * 2 + m2][es * 512 + lane8];
      __builtin_amdgcn_s_setprio(1);
#pragma unroll
      for (int es = 0; es < 4; ++es)
#pragma unroll
        for (int m2 = 0; m2 < 2; ++m2)
          s[mth * 2 + m2] = mfma16(qa[m2][es], kf[es], s[mth * 2 + m2]);
      __builtin_amdgcn_s_setprio(0);
    }
#pragma unroll
    for (int mt = 0; mt < 4; ++mt)
#pragma unroll
      for (int r = 0; r < 4; ++r)
        Ssm[0][mt * 16 + quad * 4 + r][wave * 16 + ln] = s[mt][r];
  }
  if (nch > 1) {
    const f16* kp = pkz + (((size_t)(8 + wave)) << 11) + lane8;
#pragma unroll
    for (int es = 0; es < 4; ++es) kf[es] = *(const f16x8*)(kp + es * 512);
  }
  f16x8 bvA[4], bvB[4], bvC[4], bvD[4];
  BARRIER();

  for (int i = 0; i < nch; ++i) {
    const int buf = i & 1;
    const int k0 = i << 7;
    const int ktb = i << 2;
    float4 lv[4];
    if (CROSS) {
      const float* lp = ksb + k0 + cs * 16;
#pragma unroll
      for (int ii = 0; ii < 4; ++ii) lv[ii] = *(const float4*)(lp + ii * 4);
    }
    // ---- PV(i-1) with WAR-recycled V loads (bv[ks] <- V(i).ks after use) ----
    if (i) {
#pragma unroll
      for (int mt = 0; mt < 4; ++mt) {
        f32x4 al;
#pragma unroll
        for (int r = 0; r < 4; ++r) al[r] = ash[buf ^ 1][mt * 16 + quad * 4 + r];
#pragma unroll
        for (int nt = 0; nt < 4; ++nt) oacc[mt][nt] *= al;
      }
      f16x8 pa[4];
      // ks = 0
#pragma unroll
      for (int mt = 0; mt < 4; ++mt) pa[mt] = *(const f16x8*)&Psm[buf ^ 1][mt * 16 + ln][quad * 8];
      __builtin_amdgcn_s_setprio(1);
#pragma unroll
      for (int nt = 0; nt < 4; ++nt)
#pragma unroll
        for (int mt = 0; mt < 4; ++mt)
          oacc[mt][nt] = mfma16(pa[mt], bvA[nt], oacc[mt][nt]);
      __builtin_amdgcn_s_setprio(0);
#pragma unroll
      for (int nt = 0; nt < 4; ++nt)
        bvA[nt] = *(const f16x8*)(Vw + (((size_t)(nt * nktv + ktb)) << 9));
      // ks = 1
#pragma unroll
      for (int mt = 0; mt < 4; ++mt) pa[mt] = *(const f16x8*)&Psm[buf ^ 1][mt * 16 + ln][32 + quad * 8];
      __builtin_amdgcn_s_setprio(1);
#pragma unroll
      for (int nt = 0; nt < 4; ++nt)
#pragma unroll
        for (int mt = 0; mt < 4; ++mt)
          oacc[mt][nt] = mfma16(pa[mt], bvB[nt], oacc[mt][nt]);
      __builtin_amdgcn_s_setprio(0);
#pragma unroll
      for (int nt = 0; nt < 4; ++nt)
        bvB[nt] = *(const f16x8*)(Vw + (((size_t)(nt * nktv + ktb + 1)) << 9));
      // ks = 2
#pragma unroll
      for (int mt = 0; mt < 4; ++mt) pa[mt] = *(const f16x8*)&Psm[buf ^ 1][mt * 16 + ln][64 + quad * 8];
      __builtin_amdgcn_s_setprio(1);
#pragma unroll
      for (int nt = 0; nt < 4; ++nt)
#pragma unroll
        for (int mt = 0; mt < 4; ++mt)
          oacc[mt][nt] = mfma16(pa[mt], bvC[nt], oacc[mt][nt]);
      __builtin_amdgcn_s_setprio(0);
#pragma unroll
      for (int nt = 0; nt < 4; ++nt)
        bvC[nt] = *(const f16x8*)(Vw + (((size_t)(nt * nktv + ktb + 2)) << 9));
      // ks = 3
#pragma unroll
      for (int mt = 0; mt < 4; ++mt) pa[mt] = *(const f16x8*)&Psm[buf ^ 1][mt * 16 + ln][96 + quad * 8];
      __builtin_amdgcn_s_setprio(1);
#pragma unroll
      for (int nt = 0; nt < 4; ++nt)
#pragma unroll
        for (int mt = 0; mt < 4; ++mt)
          oacc[mt][nt] = mfma16(pa[mt], bvD[nt], oacc[mt][nt]);
      __builtin_amdgcn_s_setprio(0);
#pragma unroll
      for (int nt = 0; nt < 4; ++nt)
        bvD[nt] = *(const f16x8*)(Vw + (((size_t)(nt * nktv + ktb + 3)) << 9));
    } else {
      // first phase: just load V(0)
#pragma unroll
      for (int nt = 0; nt < 4; ++nt) {
        const f16* vpn = Vw + (((size_t)(nt * nktv)) << 9);
        bvA[nt] = *(const f16x8*)(vpn);
        bvB[nt] = *(const f16x8*)(vpn + 512);
        bvC[nt] = *(const f16x8*)(vpn + 1024);
        bvD[nt] = *(const f16x8*)(vpn + 1536);
      }
    }
    // ---- QK(i+1) -> Ssm[buf^1] (Q from LDS); then K(i+2) ----
    if (i + 1 < nch) {
      f32x4 s[4];
#pragma unroll
      for (int mt = 0; mt < 4; ++mt) s[mt] = (f32x4){0.f,0.f,0.f,0.f};
#pragma unroll
      for (int mth = 0; mth < 2; ++mth) {
        f16x8 qa[2][4];
#pragma unroll
        for (int m2 = 0; m2 < 2; ++m2)
#pragma unroll
          for (int es = 0; es < 4; ++es)
            qa[m2][es] = *(const f16x8*)&Qlds[mth * 2 + m2][es * 512 + lane8];
        __builtin_amdgcn_s_setprio(1);
#pragma unroll
        for (int es = 0; es < 4; ++es)
#pragma unroll
          for (int m2 = 0; m2 < 2; ++m2)
            s[mth * 2 + m2] = mfma16(qa[m2][es], kf[es], s[mth * 2 + m2]);
        __builtin_amdgcn_s_setprio(0);
      }
#pragma unroll
      for (int mt = 0; mt < 4; ++mt)
#pragma unroll
        for (int r = 0; r < 4; ++r)
          Ssm[buf ^ 1][mt * 16 + quad * 4 + r][wave * 16 + ln] = s[mt][r];
      if (i + 2 < nch) {
        const f16* kp = pkz + (((size_t)(((i + 2) << 3) + wave)) << 11) + lane8;
#pragma unroll
        for (int es = 0; es < 4; ++es) kf[es] = *(const f16x8*)(kp + es * 512);
      }
    }
    // ---- softmax(i): thread (qs, cs) owns 16 keys of q-row qs ----
    {
      f32x4 sa[4];
#pragma unroll
      for (int ii = 0; ii < 4; ++ii) sa[ii] = *(const f32x4*)&Ssm[buf][qs][cs * 16 + ii * 4];
      float sv[16];
#pragma unroll
      for (int ii = 0; ii < 4; ++ii)
#pragma unroll
        for (int j = 0; j < 4; ++j)
          sv[ii * 4 + j] = sa[ii][j];
      if (k0 + 128 > Lk) {                    // block-uniform: last partial chunk only
        const int kb = k0 + cs * 16;
#pragma unroll
        for (int j = 0; j < 16; ++j)
          if (kb + j >= Lk) sv[j] = NEGBIG;
      }
      float m8[8];
#pragma unroll
      for (int j = 0; j < 8; ++j) m8[j] = fmaxf(sv[j], sv[j + 8]);
      float m4[4];
#pragma unroll
      for (int j = 0; j < 4; ++j) m4[j] = fmaxf(m8[j], m8[j + 4]);
      float mx = fmaxf(fmaxf(m4[0], m4[2]), fmaxf(m4[1], m4[3]));
      mx = fmaxf(mx, __shfl_xor(mx, 1));
      mx = fmaxf(mx, __shfl_xor(mx, 2));
      mx = fmaxf(mx, __shfl_xor(mx, 4));
      const float mold = msh[qs];
      const float mnew = fmaxf(mold, mx);
      const float alpha = __expf(mold - mnew);
      float ps = 0.f, pm = 0.f;
      f16x8 pv0, pv1;
#pragma unroll
      for (int j = 0; j < 16; ++j) {
        float p = __expf(sv[j] - mnew);
        ps += p;
        if (CROSS) p *= lv[j >> 2][j & 3];
        pm += p;
        if (j < 8) pv0[j] = (f16)p; else pv1[j - 8] = (f16)p;
      }
      *(f16x8*)&Psm[buf][qs][cs * 16]     = pv0;
      *(f16x8*)&Psm[buf][qs][cs * 16 + 8] = pv1;
      ps += __shfl_xor(ps, 1); ps += __shfl_xor(ps, 2); ps += __shfl_xor(ps, 4);
      msum = msum * alpha + pm;
      if (cs == 0) { msh[qs] = mnew; lsh[qs] = lsh[qs] * alpha + ps; ash[buf][qs] = alpha; }
    }
    BARRIER();
  }

  // ---- final PV(nch-1) ----
  {
    const int bl = (nch - 1) & 1;
#pragma unroll
    for (int mt = 0; mt < 4; ++mt) {
      f32x4 al;
#pragma unroll
      for (int r = 0; r < 4; ++r) al[r] = ash[bl][mt * 16 + quad * 4 + r];
#pragma unroll
      for (int nt = 0; nt < 4; ++nt) oacc[mt][nt] *= al;
    }
    f16x8 pa[4];
#pragma unroll
    for (int ks = 0; ks < 4; ++ks) {
#pragma unroll
      for (int mt = 0; mt < 4; ++mt) pa[mt] = *(const f16x8*)&Psm[bl][mt * 16 + ln][ks * 32 + quad * 8];
      __builtin_amdgcn_s_setprio(1);
#pragma unroll
      for (int nt = 0; nt < 4; ++nt) {
        const f16x8 bv = (ks == 0) ? bvA[nt] : (ks == 1) ? bvB[nt] : (ks == 2) ? bvC[nt] : bvD[nt];
#pragma unroll
        for (int mt = 0; mt < 4; ++mt)
          oacc[mt][nt] = mfma16(pa[mt], bv, oacc[mt][nt]);
      }
      __builtin_amdgcn_s_setprio(0);
    }
  }

  // ---- epilogue ----
  if (CROSS) {
    float ms = msum;
    ms += __shfl_xor(ms, 1); ms += __shfl_xor(ms, 2); ms += __shfl_xor(ms, 4);
    if (cs == 0) mask_sh[qs] = ms / lsh[qs];
    __syncthreads();
  }

  const int g0  = (im * Lq + q0) / 484;
  const int bhi = (g0 + 1) * 484 - im * Lq;             // local-q group boundary
  const bool strad = (!CROSS) && (bhi < Lq) && (bhi < q0 + 64);

  float a0 = 0.f, a1 = 0.f, a2 = 0.f;
  const float cfA = CROSS ? inorm_coef(ssIn[im * 16 + b]) : 0.f;

#pragma unroll
  for (int mt = 0; mt < 4; ++mt) {
    f32x4 li;
#pragma unroll
    for (int r = 0; r < 4; ++r) li[r] = 1.0f / lsh[mt * 16 + quad * 4 + r];
#pragma unroll
    for (int r = 0; r < 4; ++r) {
      const int q = q0 + mt * 16 + quad * 4 + r;
      if (q < Lq) {
        const size_t base = (((size_t)(im * Lq + q)) * BATCH + b) * DMODEL + wave * 64 + ln;
        if (!CROSS) {
          const bool hi = (q >= bhi);
#pragma unroll
          for (int nt = 0; nt < 4; ++nt) {
            const float y = X[base + nt * 16] + oacc[mt][nt][r] * li[r];
            X[base + nt * 16] = y;
            if (hi) a1 += y * y; else a0 += y * y;
          }
        } else {
          const float mval = mask_sh[mt * 16 + quad * 4 + r];
#pragma unroll
          for (int nt = 0; nt < 4; ++nt) {
            const float x1 = cfA * X[base + nt * 16];
            const float u = x1 * mval;
            const float v = x1 + oacc[mt][nt][r] * li[r];
            X[base + nt * 16] = u;
            Vout[base + nt * 16] = v;
            a0 += u * u; a1 += v * v; a2 += u * v;
          }
        }
      }
    }
  }
#pragma unroll
  for (int m = 32; m; m >>= 1) {
    a0 += __shfl_xor(a0, m); a1 += __shfl_xor(a1, m);
    if (CROSS) a2 += __shfl_xor(a2, m);
  }
  if (lane == 0) {
    if (!CROSS) {
      atomicAdd(ssO + g0 * 16 + b, a0);
      if (strad) atomicAdd(ssO + (g0 + 1) * 16 + b, a1);
    } else {
      const int g = im * 16 + b;
      atomicAdd(ssO + g, a0);
      atomicAdd(ssV_ + g, a1);
      atomicAdd(ssUV_ + g, a2);
    }
  }
}

// cu*cz, cv*cz per group (exact ssZ expansion)
__global__ void coef_final_kernel(const float* __restrict__ ssU, const float* __restrict__ ssV,
                                  const float* __restrict__ ssUV, float* __restrict__ AB, int n)
{
  const int t = threadIdx.x;
  if (t < n) {
    const float su = ssU[t], sv = ssV[t], suv = ssUV[t];
    const float cu = inorm_coef(su), cv = inorm_coef(sv);
    const float ssz = cu * cu * su + cv * cv * sv + 2.f * cu * cv * suv;
    const float cz = inorm_coef(ssz);
    AB[2 * t] = cu * cz; AB[2 * t + 1] = cv * cz;
  }
}

// out[b][c][p] = A*u[(im,p,b,c)] + B*v[...]  (fused final mix + inorm + transpose)
__global__ __launch_bounds__(256) void final_out_kernel(
    const float* __restrict__ u, const float* __restrict__ v,
    const float* __restrict__ AB, float* __restrict__ out, int i0)
{
  __shared__ float tile[32][33];
  const int tx = threadIdx.x, ty = threadIdx.y;
  const int pt = blockIdx.x * 32, ct = blockIdx.y * 32;
  const int z = blockIdx.z;
  const int im = z >> 4, b = z & 15;
  const float A = AB[2 * z], B = AB[2 * z + 1];
#pragma unroll
  for (int j = 0; j < 4; ++j) {
    const int p = pt + ty + 8 * j, c = ct + tx;
    float val = 0.0f;
    if (p < HWSZ) {
      const size_t idx = (((size_t)im * HWSZ + p) * BATCH + b) * DMODEL + c;
      val = A * u[idx] + B * v[idx];
    }
    tile[ty + 8 * j][tx] = val;               // tile[p_loc][c_loc]
  }
  __syncthreads();
  const int g = i0 + im;
  const size_t base = (g < 3 ? 0ull : ENC_OUT)
                    + ((size_t)(((g < 3 ? g : g - 3) * 16 + b) * 512)) * 484ull;
#pragma unroll
  for (int j = 0; j < 4; ++j) {
    const int c = ct + ty + 8 * j, p = pt + tx;
    if (p < HWSZ) out[base + (size_t)c * 484 + p] = tile[tx][ty + 8 * j];
  }
}

// ---------------- host orchestration ----------------
extern "C" void kernel_launch(void* const* d_in, const int* in_sizes, int n_in,
                              void* d_out, int out_size, void* d_ws, size_t ws_size,
                              hipStream_t stream) {
  (void)in_sizes; (void)n_in; (void)out_size;
  const float* train_feat  = (const float*)d_in[0];
  const float* test_feat   = (const float*)d_in[1];
  const float* train_label = (const float*)d_in[2];
  const float* wk_self     = (const float*)d_in[3];
  const float* bk_self     = (const float*)d_in[4];
  const float* wk_cross    = (const float*)d_in[5];
  const float* bk_cross    = (const float*)d_in[6];
  float* out = (float*)d_out;
  char* wsb  = (char*)d_ws;

  size_t off = 0;
  auto alloc = [&](size_t bytes) { size_t r = off; off = (r + bytes + 255) & ~(size_t)255; return r; };
  const size_t o_peT   = alloc(991232ull);             // [512][484] f32
  const size_t o_labT  = alloc(16ull * LKPAD * 4);
  const size_t o_ss    = alloc(4096);                  // ssE@0 ssA@128 ssU@256 ssV@384 ssUV@512 AB@640
  const size_t o_w16s  = alloc(131072);
  const size_t o_w16c  = alloc(131072);
  const size_t o_xenc  = alloc(47579136ull);           // [1452][16][512] f32
  const size_t o_p16   = alloc(6291456ull);            // 16 z x 96 tiles x 4 es x 512 f16
  const size_t o_vte   = alloc(16ull*512*LKPAD*2);     // Vt_enc fragment-major
  const size_t o_vtm   = alloc(16ull*512*LKPAD*2);     // Vt_mem fragment-major
  const size_t fixed = off;

  float* peT  = (float*)(wsb + o_peT);
  float* labT = (float*)(wsb + o_labT);
  float* ss   = (float*)(wsb + o_ss);
  f16*   w16s = (f16*)(wsb + o_w16s);
  f16*   w16c = (f16*)(wsb + o_w16c);
  float* xenc = (float*)(wsb + o_xenc);
  f16*   p16  = (f16*)(wsb + o_p16);
  f16*   vte  = (f16*)(wsb + o_vte);
  f16*   vtm  = (f16*)(wsb + o_vtm);
  float* ssE = ss, *ssA = ss + 128, *ssU = ss + 256, *ssV = ss + 384, *ssUV = ss + 512;
  float* AB  = ss + 640;

  // per image: xd + vbuf (f32) + pq16d (16 z x 32x4x512 f16) + vtd (16 z x 32x16x512 f16)
  const size_t decPer = 15859712ull * 2 + 2097152ull + 8388608ull;
  int NB = 6;
  if (fixed + (size_t)NB * decPer + 4096 > ws_size) NB = 3;
  if (fixed + (size_t)NB * decPer + 4096 > ws_size) NB = 1;

  float* xd    = (float*)(wsb + fixed);
  float* vbuf  = xd + (size_t)NB * IMG_ELEMS;
  f16*   pq16d = (f16*)(vbuf + (size_t)NB * IMG_ELEMS);
  f16*   vtd   = pq16d + (size_t)NB * 1048576ull;

  // ---- prep ----
  init_zero_kernel<<<dim3(1), dim3(1024), 0, stream>>>(ss);
  peT_kernel<<<dim3(512), dim3(256), 0, stream>>>(peT);
  build_labelT_kernel<<<dim3(64), dim3(256), 0, stream>>>(train_label, labT);
  cvt16_kernel<<<dim3(64), dim3(256), 0, stream>>>(wk_self, w16s);
  cvt16_kernel<<<dim3(64), dim3(256), 0, stream>>>(wk_cross, w16c);
  vpad_kernel<<<dim3(512, 16), dim3(96), 0, stream>>>(vte);

  // ---- encoder ----
  build_input_kernel<<<dim3(16, 16, 48), dim3(32, 8), 0, stream>>>(
      train_feat, test_feat, peT, 0, xenc, vte, /*zmul=*/0, /*col_im_step=*/484, /*nkt=*/48);
  proj_mfma_kernel<<<dim3(363), dim3(256), 0, stream>>>(xenc, w16s, bk_self, (const float*)0, p16, LENC, 96);
  attn10_kernel<0><<<dim3(23 * 16), dim3(512), 0, stream>>>(
      p16, p16, vte, (const float*)0, xenc, (float*)0, (const float*)0,
      ssE, (float*)0, (float*)0, LENC, LENC, 23, 96, 96, 48, 0, 0);
  proj_mfma_kernel<<<dim3(363), dim3(256), 0, stream>>>(xenc, w16c, bk_cross, ssE, p16, LENC, 96); // pkc
  v16t_mem_kernel<<<dim3(48, 16, 16), dim3(32, 8), 0, stream>>>(xenc, ssE, vtm);

  // ---- decoders (NB images per batch) ----
  for (int i0 = 0; i0 < 6; i0 += NB) {
    build_input_kernel<<<dim3(16, 16, NB * 16), dim3(32, 8), 0, stream>>>(
        train_feat, test_feat, peT, i0, xd, vtd, /*zmul=*/1, /*col_im_step=*/0, /*nkt=*/16);
    // self-attention (+residual+ssA fused)
    proj_mfma_kernel<<<dim3(NB * 121), dim3(256), 0, stream>>>(xd, w16s, bk_self, (const float*)0, pq16d, HWSZ, 32);
    attn10_kernel<0><<<dim3(8 * 16 * NB), dim3(512), 0, stream>>>(
        pq16d, pq16d, vtd, (const float*)0, xd, (float*)0, (const float*)0,
        ssA + i0 * 16, (float*)0, (float*)0, HWSZ, HWSZ, 8, 32, 32, 16, 0, 0);
    // cross-attention (mask/u/v/ssU/ssV/ssUV fused)
    proj_mfma_kernel<<<dim3(NB * 121), dim3(256), 0, stream>>>(xd, w16c, bk_cross, ssA + i0 * 16, pq16d, HWSZ, 32);
    attn10_kernel<1><<<dim3(8 * 16 * NB), dim3(512), 0, stream>>>(
        pq16d, p16 /*pkc*/, vtm, labT, xd, vbuf, ssA + i0 * 16,
        ssU + i0 * 16, ssV + i0 * 16, ssUV + i0 * 16, HWSZ, LENC, 8, 32, 96, 48, 1, 1);
    coef_final_kernel<<<dim3(1), dim3(128), 0, stream>>>(
        ssU + i0 * 16, ssV + i0 * 16, ssUV + i0 * 16, AB + i0 * 32, NB * 16);
    final_out_kernel<<<dim3(16, 16, NB * 16), dim3(32, 8), 0, stream>>>(
        xd, vbuf, AB + i0 * 32, out, i0);
  }
}